// Round 4
// baseline (235.177 us; speedup 1.0000x reference)
//
#include <hip/hip_runtime.h>
#include <hip/hip_cooperative_groups.h>
#include <math.h>

namespace cg = cooperative_groups;

#define H 2048
#define W 2048
#define SEG 32
#define L 64            // rows per segment (H/SEG)
#define BIG (1 << 20)
#define DCLAMP 2900     // > sqrt(2047^2+2048^2); f <= 8.41e6 exact in fp32
#define NBLK 256
#define NTHR 256
#define RPB (H / NBLK)  // 8 rows per block in phase D
#define CPT (W / NTHR)  // 8 pixels per thread per row

// Single cooperative kernel. Block b: bx=b&7 -> column group, s=b>>3 -> segment.
// LDS carries the local column-scan between phases A and C (no global round-trip).
__global__ void __launch_bounds__(256, 1)
edt_fused(const float* __restrict__ img, int* __restrict__ out,
          int* __restrict__ A, int* __restrict__ B,
          int* __restrict__ CD, int* __restrict__ CU,
          unsigned int* __restrict__ maxp) {
    cg::grid_group grid = cg::this_grid();
    __shared__ unsigned int dloc[L][NTHR];  // 64 KB: BIG-encoded local down-scan
    __shared__ float srow[W];               // 8 KB: phase D row buffer
    __shared__ float smax[4];

    const int tid = threadIdx.x;
    const int blk = blockIdx.x;
    const int bx = blk & 7;
    const int s  = blk >> 3;
    const int j  = bx * NTHR + tid;
    const int r0 = s * L;

    if (blk == 0 && tid == 0) *maxp = 0u;

    // ---- Phase A: local down-scan (img -> LDS), write per-segment summaries.
    // d = BIG sentinel means "no background yet"; d-BIG = rows since seg top.
    int d = BIG;
    int first = -1;  // lowest row index in segment that is background
#pragma unroll 8
    for (int i = 0; i < L; ++i) {
        bool z = img[(size_t)(r0 + i) * W + j] <= 0.5f;
        d = z ? 0 : d + 1;
        first = (z && first < 0) ? i : first;
        dloc[i][tid] = (unsigned int)d;
    }
    A[s * W + j] = d;                              // bottom-row down value
    B[s * W + j] = (first >= 0) ? first : BIG + L; // top-row up value

    grid.sync();

    // ---- Phase B: resolve carries across segments (2048 worker threads).
    {
        int gt = blk * NTHR + tid;
        if (gt < W) {
            int av[SEG];
#pragma unroll
            for (int t = 0; t < SEG; ++t) av[t] = A[t * W + gt];
            int c = BIG;
#pragma unroll
            for (int t = 0; t < SEG; ++t) {
                CD[t * W + gt] = c;
                c = (av[t] < BIG) ? av[t] : av[t] - BIG + c;
            }
#pragma unroll
            for (int t = 0; t < SEG; ++t) av[t] = B[t * W + gt];
            c = BIG;
#pragma unroll
            for (int t = SEG - 1; t >= 0; --t) {
                CU[t * W + gt] = c;
                c = (av[t] < BIG) ? av[t] : av[t] - BIG + c;
            }
        }
    }

    grid.sync();

    // ---- Phase C: combine LDS down-scan with carries; write f = d1^2 to out.
    {
        float* fbuf = (float*)out;
        int dc = CD[s * W + j];
        int u  = CU[s * W + j];
#pragma unroll 8
        for (int i = L - 1; i >= 0; --i) {
            int v = (int)dloc[i][tid];
            bool z = (v == 0);
            u = z ? 0 : u + 1;
            int dv = (v < BIG) ? v : v - BIG + dc;
            int dd = min(min(dv, u), DCLAMP);
            float fd = (float)dd;
            fbuf[(size_t)(r0 + i) * W + j] = z ? 0.0f : fd * fd;
        }
    }

    grid.sync();

    // ---- Phase D: exact row pass (early exit) on 8 rows/block; dist in regs.
    float res[RPB][CPT];
    float lmax = 0.0f;
    const float* fbuf = (const float*)out;
    for (int t = 0; t < RPB; ++t) {
        int r = blk * RPB + t;
        __syncthreads();
#pragma unroll
        for (int k = 0; k < CPT; ++k)
            srow[tid + NTHR * k] = fbuf[(size_t)r * W + tid + NTHR * k];
        __syncthreads();
#pragma unroll
        for (int k = 0; k < CPT; ++k) {
            int jj = tid + NTHR * k;
            float best = srow[jj];
            for (int dd = 1; dd <= 2048 && (float)(dd * dd) < best; ++dd) {
                float q = (float)(dd * dd);
                int jm = jj - dd, jp = jj + dd;
                if (jm >= 0) best = fminf(best, srow[jm] + q);
                if (jp < W)  best = fminf(best, srow[jp] + q);
            }
            float rr = sqrtf(best);
            res[t][k] = rr;
            lmax = fmaxf(lmax, rr);
        }
    }
    for (int o = 32; o > 0; o >>= 1) lmax = fmaxf(lmax, __shfl_down(lmax, o, 64));
    if ((tid & 63) == 0) smax[tid >> 6] = lmax;
    __syncthreads();
    if (tid == 0)
        atomicMax(maxp, __float_as_uint(fmaxf(fmaxf(smax[0], smax[1]),
                                              fmaxf(smax[2], smax[3]))));

    grid.sync();

    // ---- Phase E: normalize regs, single int32 store (uint8 semantics).
    float m = __uint_as_float(*maxp);
    for (int t = 0; t < RPB; ++t) {
        int r = blk * RPB + t;
#pragma unroll
        for (int k = 0; k < CPT; ++k) {
            float dv = res[t][k];
            float v = (m > 0.0f) ? (dv / m * 255.0f) : dv;  // match numpy op order
            v = fminf(fmaxf(v, 0.0f), 255.0f);
            out[(size_t)r * W + tid + NTHR * k] = (int)v;   // trunc, like astype(uint8)
        }
    }
}

extern "C" void kernel_launch(void* const* d_in, const int* in_sizes, int n_in,
                              void* d_out, int out_size, void* d_ws, size_t ws_size,
                              hipStream_t stream) {
    const float* img = (const float*)d_in[0];
    int* out = (int*)d_out;

    // ws: A | B | CD | CU (256 KB each) | maxp (4 B)
    char* ws = (char*)d_ws;
    int* A  = (int*)ws;
    int* B  = A + SEG * W;
    int* CD = B + SEG * W;
    int* CU = CD + SEG * W;
    unsigned int* maxp = (unsigned int*)(CU + SEG * W);

    void* args[] = {(void*)&img, (void*)&out, (void*)&A, (void*)&B,
                    (void*)&CD, (void*)&CU, (void*)&maxp};
    hipLaunchCooperativeKernel((const void*)edt_fused, dim3(NBLK), dim3(NTHR),
                               args, 0, stream);
}

// Round 5
// 111.743 us; speedup vs baseline: 2.1046x; 2.1046x over previous
//
#include <hip/hip_runtime.h>
#include <math.h>

#define H 2048
#define W 2048
#define SEG 256
#define L 8             // rows per segment
#define BIG (1 << 20)
#define DCLAMP 2900     // > max possible distance; f <= 8.41e6, exact in fp32

// ---------------------------------------------------------------------------
// K1: per (column-group, segment): 8-row local down-scan, 4 columns/thread via
// float4. Byte-encodes result: v in 0..7 = exact down-dist (0 <=> background);
// v in 129..136 = 128 + (rows since segment top), i.e. BIG-encoded.
// Also writes per-segment summaries A (bottom down value), B (top up value).
// Thread (0,0,0) zero-inits maxp (stream-ordered before K3's atomics).
// ---------------------------------------------------------------------------
__global__ void k1_down(const float* __restrict__ img, unsigned char* __restrict__ down,
                        int* __restrict__ A, int* __restrict__ B,
                        unsigned int* __restrict__ maxp) {
    const int tid = threadIdx.x;
    const int bx = blockIdx.x;          // 0..1
    const int s  = blockIdx.y;          // 0..255
    const int j0 = bx * 1024 + tid * 4;
    const int r0 = s * L;
    if (bx == 0 && s == 0 && tid == 0) *maxp = 0u;

    int d[4]  = {BIG, BIG, BIG, BIG};
    int fb[4] = {-1, -1, -1, -1};
#pragma unroll
    for (int i = 0; i < L; ++i) {
        const float4 v = *(const float4*)(img + (size_t)(r0 + i) * W + j0);
        float vv[4] = {v.x, v.y, v.z, v.w};
        unsigned enc4 = 0;
#pragma unroll
        for (int k = 0; k < 4; ++k) {
            bool z = vv[k] <= 0.5f;                 // background
            d[k] = z ? 0 : d[k] + 1;
            fb[k] = (z && fb[k] < 0) ? i : fb[k];
            unsigned e = (d[k] < BIG) ? (unsigned)d[k] : (unsigned)(128 + (d[k] - BIG));
            enc4 |= e << (8 * k);
        }
        *(unsigned*)(down + (size_t)(r0 + i) * W + j0) = enc4;
    }
    *(int4*)(A + (size_t)s * W + j0) =
        make_int4(d[0], d[1], d[2], d[3]);
    *(int4*)(B + (size_t)s * W + j0) =
        make_int4(fb[0] >= 0 ? fb[0] : BIG + L, fb[1] >= 0 ? fb[1] : BIG + L,
                  fb[2] >= 0 ? fb[2] : BIG + L, fb[3] >= 0 ? fb[3] : BIG + L);
}

// ---------------------------------------------------------------------------
// K2: resolve carries across the 256 segments. One thread per (column, dir):
// 4096 threads. The 256-step recurrence has a VALU-only dependency chain;
// all loads/stores are address-independent and pipeline under unrolling.
// CD[s][j] = down-dist at row just above segment s; CU[s][j] = up-dist at
// row just below segment s (both BIG-encoded if out of range).
// ---------------------------------------------------------------------------
__global__ void k2_carry(const int* __restrict__ A, const int* __restrict__ B,
                         int* __restrict__ CD, int* __restrict__ CU) {
    int gt = blockIdx.x * blockDim.x + threadIdx.x;   // 0..4095
    int col = gt & (W - 1);
    if (gt < W) {
        int c = BIG;
#pragma unroll 8
        for (int s = 0; s < SEG; ++s) {
            int a = A[(size_t)s * W + col];
            CD[(size_t)s * W + col] = c;
            c = (a < BIG) ? a : a - BIG + c;
        }
    } else {
        int c = BIG;
#pragma unroll 8
        for (int s = SEG - 1; s >= 0; --s) {
            int b = B[(size_t)s * W + col];
            CU[(size_t)s * W + col] = c;
            c = (b < BIG) ? b : b - BIG + c;
        }
    }
}

// ---------------------------------------------------------------------------
// K3: one block per 8-row segment, full 2048-column width. Decodes the down
// bytes + carries into f = d1^2 directly in LDS (f never touches HBM), then
// runs the exact early-exit row pass on each of its 8 rows, writes sqrt(D)
// to out (fp32), and contributes the block max via one atomicMax.
// Early-exit exactness: candidates at offset d cost >= d^2 and d expands
// upward, so stopping at d*d >= best is exact. Hard-bounded at d<=2048.
// ---------------------------------------------------------------------------
__global__ void __launch_bounds__(256)
k3_main(const unsigned char* __restrict__ down, const int* __restrict__ CD,
        const int* __restrict__ CU, float* __restrict__ dist,
        unsigned int* __restrict__ maxp) {
    __shared__ float ftile[L][W];   // 64 KB
    __shared__ float smax[4];
    const int tid = threadIdx.x;
    const int s = blockIdx.x;
    const int r0 = s * L;
    const int c0 = tid * 8;         // this thread owns columns c0..c0+7

    // carries for my 8 columns
    int4 a0 = *(const int4*)(CD + (size_t)s * W + c0);
    int4 a1 = *(const int4*)(CD + (size_t)s * W + c0 + 4);
    int4 b0 = *(const int4*)(CU + (size_t)s * W + c0);
    int4 b1 = *(const int4*)(CU + (size_t)s * W + c0 + 4);
    int dc[8] = {a0.x, a0.y, a0.z, a0.w, a1.x, a1.y, a1.z, a1.w};
    int u[8]  = {b0.x, b0.y, b0.z, b0.w, b1.x, b1.y, b1.z, b1.w};

    // bottom-to-top: decode down byte, run up-chain, emit f into LDS
    for (int i = L - 1; i >= 0; --i) {
        uint2 wv = *(const uint2*)(down + (size_t)(r0 + i) * W + c0);
        float fr[8];
#pragma unroll
        for (int k = 0; k < 8; ++k) {
            unsigned v = ((k < 4 ? wv.x : wv.y) >> (8 * (k & 3))) & 0xffu;
            bool z = (v == 0);
            u[k] = z ? 0 : u[k] + 1;
            int dv = (v < 128u) ? (int)v : (int)(v - 128u) + dc[k];
            int dd = min(min(dv, u[k]), DCLAMP);
            float fd = (float)dd;
            fr[k] = z ? 0.0f : fd * fd;
        }
        *(float4*)&ftile[i][c0]     = make_float4(fr[0], fr[1], fr[2], fr[3]);
        *(float4*)&ftile[i][c0 + 4] = make_float4(fr[4], fr[5], fr[6], fr[7]);
    }
    __syncthreads();

    float lmax = 0.0f;
    for (int i = 0; i < L; ++i) {
        float res[8];
#pragma unroll
        for (int k = 0; k < 8; ++k) {
            int jj = c0 + k;
            float best = ftile[i][jj];
            for (int dd = 1; dd <= 2048 && (float)(dd * dd) < best; ++dd) {
                float q = (float)(dd * dd);
                int jm = jj - dd, jp = jj + dd;
                if (jm >= 0) best = fminf(best, ftile[i][jm] + q);
                if (jp < W)  best = fminf(best, ftile[i][jp] + q);
            }
            float r = sqrtf(best);
            res[k] = r;
            lmax = fmaxf(lmax, r);
        }
        *(float4*)(dist + (size_t)(r0 + i) * W + c0)     = make_float4(res[0], res[1], res[2], res[3]);
        *(float4*)(dist + (size_t)(r0 + i) * W + c0 + 4) = make_float4(res[4], res[5], res[6], res[7]);
    }

    for (int o = 32; o > 0; o >>= 1) lmax = fmaxf(lmax, __shfl_down(lmax, o, 64));
    if ((tid & 63) == 0) smax[tid >> 6] = lmax;
    __syncthreads();
    if (tid == 0)
        atomicMax(maxp, __float_as_uint(fmaxf(fmaxf(smax[0], smax[1]),
                                              fmaxf(smax[2], smax[3]))));
}

// ---------------------------------------------------------------------------
// K5: in-place normalize, float4 -> int4 (uint8 semantics: trunc(d/m*255)).
// Same thread reads & writes the same elements — aliasing-safe.
// ---------------------------------------------------------------------------
__global__ void k5_norm(int* __restrict__ out, const unsigned int* __restrict__ maxp) {
    size_t idx = ((size_t)blockIdx.x * blockDim.x + threadIdx.x) * 4;
    float m = __uint_as_float(*maxp);
    float4 dv = *(const float4*)((const float*)out + idx);
    float r[4] = {dv.x, dv.y, dv.z, dv.w};
    int o[4];
#pragma unroll
    for (int k = 0; k < 4; ++k) {
        float v = (m > 0.0f) ? (r[k] / m * 255.0f) : r[k];  // numpy op order
        v = fminf(fmaxf(v, 0.0f), 255.0f);
        o[k] = (int)v;                                      // trunc, like astype(uint8)
    }
    *(int4*)(out + idx) = make_int4(o[0], o[1], o[2], o[3]);
}

extern "C" void kernel_launch(void* const* d_in, const int* in_sizes, int n_in,
                              void* d_out, int out_size, void* d_ws, size_t ws_size,
                              hipStream_t stream) {
    const float* img = (const float*)d_in[0];
    int* out = (int*)d_out;

    // ws: down bytes (4 MB) | A | B | CD | CU (2 MB each) | maxp
    char* ws = (char*)d_ws;
    unsigned char* down = (unsigned char*)ws;
    int* A  = (int*)(ws + (size_t)H * W);
    int* B  = A + (size_t)SEG * W;
    int* CD = B + (size_t)SEG * W;
    int* CU = CD + (size_t)SEG * W;
    unsigned int* maxp = (unsigned int*)(CU + (size_t)SEG * W);

    dim3 blk(256);
    k1_down <<<dim3(2, SEG), blk, 0, stream>>>(img, down, A, B, maxp);
    k2_carry<<<dim3(2 * W / 256), blk, 0, stream>>>(A, B, CD, CU);
    k3_main <<<dim3(SEG), blk, 0, stream>>>(down, CD, CU, (float*)out, maxp);
    k5_norm <<<dim3(H * W / 1024), blk, 0, stream>>>(out, maxp);
}